// Round 4
// baseline (283.732 us; speedup 1.0000x reference)
//
#include <hip/hip_runtime.h>
#include <math.h>

#define D_MODEL 2048
#define KB_ 64
#define NCHUNK 32

typedef __bf16 bf16;
typedef __attribute__((ext_vector_type(8))) __bf16 bf16x8;
typedef __attribute__((ext_vector_type(4))) __bf16 bf16x4;
typedef __attribute__((ext_vector_type(4))) float f32x4;

// ---- workspace layout (float offsets) ----
#define OFF_S      0                            // bufS [32][64][2048]
#define OFF_F      (32 * 64 * 2048)             // bufF [32][64][2048]
#define OFF_NORMS  (2 * 32 * 64 * 2048)         // [32][64]
#define OFF_VR     (OFF_NORMS + 2048)           // [2048]
#define OFF_VI     (OFF_VR + 2048)              // [2048]
#define OFF_DSQ    (OFF_VI + 2048)              // [64]  (vr|vi|dsq contiguous)
#define OFF_CTX    (OFF_DSQ + 64)               // [2048]

// ---------------------------------------------------------------------------
// K1: single-pass chunk projection. Block (dt, j), j in [0,33):
//   j<32 : stage chunk_j = batch-mean of scan rows [j*256,(j+1)*256) (d-tile dt)
//          bufS[j]   += A_hi @ chunk_j     (window j, second half)
//          bufF[j+1] += A_lo @ chunk_j     (window j+1, first half; skip j=31)
//   j=32 : stage buf[256:512) -> bufF[0] = A_lo @ buf_tail
// Each scan byte is fetched exactly once (vs 2x before).
// ---------------------------------------------------------------------------
__device__ __forceinline__ void load_stage(
    const float* __restrict__ scan, const float* __restrict__ buf,
    int j, int nb, int n0, int dcol, float4* ra, float4* rb)
{
  if (j == 32) {
    const float* bp = buf + (256 + nb * 64 + n0) * 2048 + dcol;
#pragma unroll
    for (int i = 0; i < 4; ++i) { ra[i] = *(const float4*)(bp + i * 2048); rb[i] = ra[i]; }
  } else {
    const float* p0 = scan + (j * 256 + nb * 64 + n0) * 2048 + dcol;
    const float* p1 = p0 + 8192 * 2048;
#pragma unroll
    for (int i = 0; i < 4; ++i) {
      ra[i] = *(const float4*)(p0 + i * 2048);
      rb[i] = *(const float4*)(p1 + i * 2048);
    }
  }
}

__device__ __forceinline__ void store_stage(
    bf16* Bsbuf, int n0, int d4, const float4* ra, const float4* rb)
{
  float4 m0 = make_float4(0.5f * (ra[0].x + rb[0].x), 0.5f * (ra[0].y + rb[0].y),
                          0.5f * (ra[0].z + rb[0].z), 0.5f * (ra[0].w + rb[0].w));
  float4 m1 = make_float4(0.5f * (ra[1].x + rb[1].x), 0.5f * (ra[1].y + rb[1].y),
                          0.5f * (ra[1].z + rb[1].z), 0.5f * (ra[1].w + rb[1].w));
  float4 m2 = make_float4(0.5f * (ra[2].x + rb[2].x), 0.5f * (ra[2].y + rb[2].y),
                          0.5f * (ra[2].z + rb[2].z), 0.5f * (ra[2].w + rb[2].w));
  float4 m3 = make_float4(0.5f * (ra[3].x + rb[3].x), 0.5f * (ra[3].y + rb[3].y),
                          0.5f * (ra[3].z + rb[3].z), 0.5f * (ra[3].w + rb[3].w));
  bf16x4 e0 = {(bf16)m0.x, (bf16)m1.x, (bf16)m2.x, (bf16)m3.x};
  bf16x4 e1 = {(bf16)m0.y, (bf16)m1.y, (bf16)m2.y, (bf16)m3.y};
  bf16x4 e2 = {(bf16)m0.z, (bf16)m1.z, (bf16)m2.z, (bf16)m3.z};
  bf16x4 e3 = {(bf16)m0.w, (bf16)m1.w, (bf16)m2.w, (bf16)m3.w};
  *(bf16x4*)(Bsbuf + (d4 + 0) * 72 + n0) = e0;
  *(bf16x4*)(Bsbuf + (d4 + 1) * 72 + n0) = e1;
  *(bf16x4*)(Bsbuf + (d4 + 2) * 72 + n0) = e2;
  *(bf16x4*)(Bsbuf + (d4 + 3) * 72 + n0) = e3;
}

__global__ __launch_bounds__(256, 4) void k1_part(
    const float* __restrict__ scan, const float* __restrict__ buf,
    const float* __restrict__ cheby, float* __restrict__ bufS,
    float* __restrict__ bufF, float* __restrict__ vzero)
{
  __shared__ bf16 Bs[2][64 * 72];

  const int t = threadIdx.x;
  const int dt = blockIdx.x;     // 0..31 d-tile
  const int j  = blockIdx.y;     // 0..32 chunk (32 = buf tail)
  const int w = t >> 6, lane = t & 63;
  const int quad = lane >> 4, r16 = lane & 15;
  const int d0 = dt * 64;
  const int n0 = (t >> 4) * 4;
  const int d4 = (t & 15) * 4;
  const int dcol = d0 + d4;

  if (dt == 0 && j == 0) {
    for (int i = t; i < 4160; i += 256) vzero[i] = 0.f;   // vr | vi | dsq
  }

  f32x4 accS[4], accF[4];
#pragma unroll
  for (int tn = 0; tn < 4; ++tn) {
    accS[tn] = (f32x4){0.f, 0.f, 0.f, 0.f};
    accF[tn] = (f32x4){0.f, 0.f, 0.f, 0.f};
  }

  float4 ra[4], rb[4];
  load_stage(scan, buf, j, 0, n0, dcol, ra, rb);
  store_stage(Bs[0], n0, d4, ra, rb);
  __syncthreads();

  for (int nb = 0; nb < 4; ++nb) {
    if (nb < 3) load_stage(scan, buf, j, nb + 1, n0, dcol, ra, rb);

    // A-fragments: cheby row (band), cols nb*64.. (A_lo) and 256+nb*64.. (A_hi)
    const float* ab = cheby + (w * 16 + r16) * 512 + nb * 64 + quad * 8;
    float4 f0 = *(const float4*)(ab);
    float4 f1 = *(const float4*)(ab + 4);
    float4 f2 = *(const float4*)(ab + 32);
    float4 f3 = *(const float4*)(ab + 36);
    float4 g0 = *(const float4*)(ab + 256);
    float4 g1 = *(const float4*)(ab + 260);
    float4 g2 = *(const float4*)(ab + 288);
    float4 g3 = *(const float4*)(ab + 292);
    bf16x8 aF[2] = {{(bf16)f0.x, (bf16)f0.y, (bf16)f0.z, (bf16)f0.w,
                     (bf16)f1.x, (bf16)f1.y, (bf16)f1.z, (bf16)f1.w},
                    {(bf16)f2.x, (bf16)f2.y, (bf16)f2.z, (bf16)f2.w,
                     (bf16)f3.x, (bf16)f3.y, (bf16)f3.z, (bf16)f3.w}};
    bf16x8 aS[2] = {{(bf16)g0.x, (bf16)g0.y, (bf16)g0.z, (bf16)g0.w,
                     (bf16)g1.x, (bf16)g1.y, (bf16)g1.z, (bf16)g1.w},
                    {(bf16)g2.x, (bf16)g2.y, (bf16)g2.z, (bf16)g2.w,
                     (bf16)g3.x, (bf16)g3.y, (bf16)g3.z, (bf16)g3.w}};

    const bf16* bsr = Bs[nb & 1];
#pragma unroll
    for (int ks = 0; ks < 2; ++ks) {
#pragma unroll
      for (int tn = 0; tn < 4; ++tn) {
        bf16x8 bfr = *(const bf16x8*)(bsr + (tn * 16 + r16) * 72 + ks * 32 + quad * 8);
        accS[tn] = __builtin_amdgcn_mfma_f32_16x16x32_bf16(aS[ks], bfr, accS[tn], 0, 0, 0);
        accF[tn] = __builtin_amdgcn_mfma_f32_16x16x32_bf16(aF[ks], bfr, accF[tn], 0, 0, 0);
      }
    }

    if (nb < 3) store_stage(Bs[(nb + 1) & 1], n0, d4, ra, rb);
    __syncthreads();
  }

  // epilogue: scale + partial stores
  const float scale = 2.0f / 512.0f;
  const int jF = (j == 32) ? 0 : j + 1;
#pragma unroll
  for (int tn = 0; tn < 4; ++tn) {
#pragma unroll
    for (int rq = 0; rq < 4; ++rq) {
      int band = w * 16 + quad * 4 + rq;
      float sc = (band == 0) ? scale * 0.5f : scale;
      int dd = d0 + tn * 16 + r16;
      if (j < 32) bufS[(j * 64 + band) * 2048 + dd] = accS[tn][rq] * sc;
      if (j != 31) bufF[(jF * 64 + band) * 2048 + dd] = accF[tn][rq] * sc;
    }
  }
}

// ---------------------------------------------------------------------------
// K2: norms (recomputed from bufS+bufF, L2-resident) + bind (atomic vr/vi)
//     + delta partials (atomic dsq). grid (32, 32): bx -> xi=bx>>2, kg=bx&3.
// ---------------------------------------------------------------------------
__global__ __launch_bounds__(256) void k2_bind(
    const float* __restrict__ bufS, const float* __restrict__ bufF,
    const float* __restrict__ rr, const float* __restrict__ ri,
    float* __restrict__ vr, float* __restrict__ vi,
    float* __restrict__ dsq, float* __restrict__ norms)
{
  __shared__ float red[4][16];
  __shared__ float inv_s[16];
  const int t = threadIdx.x, lane = t & 63, wv = t >> 6;
  const int xi = blockIdx.x >> 2, kg = blockIdx.x & 3;
  const int c = blockIdx.y;

  // Phase A: sumsq over all 2048 d for this block's 16 bands
  float sq16[16];
#pragma unroll
  for (int kk = 0; kk < 16; ++kk) {
    int k = kg * 16 + kk;
    const float* ps = bufS + (c * 64 + k) * 2048 + t * 8;
    const float* pf = bufF + (c * 64 + k) * 2048 + t * 8;
    float4 s0 = *(const float4*)(ps);
    float4 s1 = *(const float4*)(ps + 4);
    float4 f0 = *(const float4*)(pf);
    float4 f1 = *(const float4*)(pf + 4);
    float a0 = s0.x + f0.x, a1 = s0.y + f0.y, a2 = s0.z + f0.z, a3 = s0.w + f0.w;
    float a4 = s1.x + f1.x, a5 = s1.y + f1.y, a6 = s1.z + f1.z, a7 = s1.w + f1.w;
    float s = a0 * a0 + a1 * a1 + a2 * a2 + a3 * a3 +
              a4 * a4 + a5 * a5 + a6 * a6 + a7 * a7;
#pragma unroll
    for (int o = 32; o > 0; o >>= 1) s += __shfl_down(s, o, 64);
    sq16[kk] = s;
  }
  if (lane == 0) {
#pragma unroll
    for (int kk = 0; kk < 16; ++kk) red[wv][kk] = sq16[kk];
  }
  __syncthreads();
  if (t < 16) {
    float s = red[0][t] + red[1][t] + red[2][t] + red[3][t];
    float nrm = fmaxf(sqrtf(s), 1e-12f);
    inv_s[t] = 1.0f / nrm;
    if (xi == 0) norms[c * 64 + kg * 16 + t] = nrm;
  }
  __syncthreads();

  // Phase B: bind (+ delta for c==31)
  const int d = xi * 256 + t;
  const float wc = 0.1f * powf(0.9f, (float)(31 - c));
  float ar = 0.f, ai = 0.f;
  if (c == 31) {
#pragma unroll 4
    for (int kk = 0; kk < 16; ++kk) {
      int k = kg * 16 + kk;
      float cf = bufS[(31 * 64 + k) * 2048 + d] + bufF[(31 * 64 + k) * 2048 + d];
      float cn = cf * inv_s[kk];
      ar += cn * rr[k * 2048 + d];
      ai += cn * ri[k * 2048 + d];
      float cp = bufS[(30 * 64 + k) * 2048 + d] + bufF[(30 * 64 + k) * 2048 + d];
      float diff = cf - cp;
      float sqv = diff * diff;
#pragma unroll
      for (int o = 32; o > 0; o >>= 1) sqv += __shfl_down(sqv, o, 64);
      if (lane == 0) atomicAdd(&dsq[k], sqv);
    }
  } else {
#pragma unroll 4
    for (int kk = 0; kk < 16; ++kk) {
      int k = kg * 16 + kk;
      float cf = bufS[(c * 64 + k) * 2048 + d] + bufF[(c * 64 + k) * 2048 + d];
      float cn = cf * inv_s[kk];
      ar += cn * rr[k * 2048 + d];
      ai += cn * ri[k * 2048 + d];
    }
  }
  atomicAdd(&vr[d], wc * ar);
  atomicAdd(&vi[d], wc * ai);
}

// ---------------------------------------------------------------------------
// K3: cnorms EMA + top-8 (from dsq) + delta out + vr/vi out + ctx
// ---------------------------------------------------------------------------
__global__ __launch_bounds__(256) void k3_ctx(
    const float* __restrict__ norms, const float* __restrict__ vr,
    const float* __restrict__ vi, const float* __restrict__ rr,
    const float* __restrict__ ri, const float* __restrict__ wb,
    const float* __restrict__ dsq, float* __restrict__ dout,
    float* __restrict__ ctx)
{
  __shared__ float cn_s[64];
  __shared__ int top_s[8];
  __shared__ float wgt_s[8];
  const int t = threadIdx.x;
  const int d = blockIdx.x * 256 + t;
  if (t < 64) {
    float s = 0.f;
    for (int c = 0; c < NCHUNK; ++c) s = 0.9f * s + 0.1f * norms[c * 64 + t];
    cn_s[t] = fmaxf(s, 1e-12f);
    if (blockIdx.x == 0) dout[D_MODEL + t] = sqrtf(dsq[t]);
  }
  if (t == 0) {
    unsigned long long taken = 0ULL;
    for (int jj = 0; jj < 8; ++jj) {
      float best = -1.f;
      int bi = 0;
      for (int k = 0; k < 64; ++k) {
        float dv = dsq[k];          // sqrt monotone; compare pre-sqrt
        if (!((taken >> k) & 1ULL) && dv > best) { best = dv; bi = k; }
      }
      taken |= (1ULL << bi);
      top_s[jj] = bi;
      wgt_s[jj] = log1pf(expf(wb[bi]));  // softplus
    }
  }
  __syncthreads();
  float sr = vr[d], si = vi[d];
  dout[D_MODEL + KB_ + d] = sr;
  dout[D_MODEL + KB_ + D_MODEL + d] = si;
  float cx = 0.f;
#pragma unroll
  for (int jj = 0; jj < 8; ++jj) {
    int k = top_s[jj];
    cx += wgt_s[jj] * (sr * rr[k * D_MODEL + d] + si * ri[k * D_MODEL + d]) * cn_s[k];
  }
  ctx[d] = cx;
}

// K4: out[d] = sigmoid(gate) * sum_e ctx[e]*Wp[d][e]; one wave per row
__global__ __launch_bounds__(256) void k4_gemv(
    const float* __restrict__ Wp, const float* __restrict__ ctx,
    const float* __restrict__ gate, float* __restrict__ dout)
{
  const int tid = threadIdx.x;
  const int lane = tid & 63;
  const int w = tid >> 6;
  const int row = blockIdx.x * 4 + w;
  const float* p = Wp + row * D_MODEL;
  float s = 0.f;
#pragma unroll
  for (int i = 0; i < 8; ++i) {
    int e = lane * 4 + i * 256;
    float4 wv = *(const float4*)(p + e);
    float4 cv = *(const float4*)(ctx + e);
    s += wv.x * cv.x + wv.y * cv.y + wv.z * cv.z + wv.w * cv.w;
  }
#pragma unroll
  for (int o = 32; o > 0; o >>= 1) s += __shfl_down(s, o, 64);
  if (lane == 0) {
    float sig = 1.f / (1.f + expf(-gate[0]));
    dout[row] = s * sig;
  }
}

extern "C" void kernel_launch(void* const* d_in, const int* in_sizes, int n_in,
                              void* d_out, int out_size, void* d_ws, size_t ws_size,
                              hipStream_t stream) {
  const float* scan  = (const float*)d_in[0];
  const float* buf   = (const float*)d_in[1];
  const float* rr    = (const float*)d_in[2];
  const float* ri    = (const float*)d_in[3];
  const float* wb    = (const float*)d_in[4];
  const float* Wp    = (const float*)d_in[5];
  const float* gate  = (const float*)d_in[6];
  const float* cheby = (const float*)d_in[7];
  float* out = (float*)d_out;
  float* ws = (float*)d_ws;

  float* bufS  = ws + OFF_S;
  float* bufF  = ws + OFF_F;
  float* norms = ws + OFF_NORMS;
  float* vr    = ws + OFF_VR;
  float* vi    = ws + OFF_VI;
  float* dsq   = ws + OFF_DSQ;
  float* ctx   = ws + OFF_CTX;

  k1_part<<<dim3(32, 33), 256, 0, stream>>>(scan, buf, cheby, bufS, bufF, vr);
  k2_bind<<<dim3(32, 32), 256, 0, stream>>>(bufS, bufF, rr, ri, vr, vi, dsq, norms);
  k3_ctx<<<8, 256, 0, stream>>>(norms, vr, vi, rr, ri, wb, dsq, out, ctx);
  k4_gemv<<<512, 256, 0, stream>>>(Wp, ctx, gate, out);
}